// Round 17
// baseline (237.341 us; speedup 1.0000x reference)
//
#include <hip/hip_runtime.h>

#define LORA_RANK 16
#define SCALING 2.0f

using bf16x8 = __attribute__((ext_vector_type(8))) __bf16;
using bf16x4 = __attribute__((ext_vector_type(4))) __bf16;
using f32x4  = __attribute__((ext_vector_type(4))) float;
using i32x4  = __attribute__((ext_vector_type(4))) int;

#define GLB(p) ((const __attribute__((address_space(1))) void*)(p))
#define LDS(p) ((__attribute__((address_space(3))) void*)(p))

// ---------------------------------------------------------------------------
// L[o][i] = SCALING * sum_r lB[o][r]*lA[r][i]  -> bf16 into d_ws scratch.
// (LDS-tiled: lA slice loaded once per 64-row block -> 16 MB total traffic.)
// ---------------------------------------------------------------------------
__global__ __launch_bounds__(256) void lora_mat_kernel(
    const float* __restrict__ lA, const float* __restrict__ lB,
    __bf16* __restrict__ L, int N, int K)
{
    const int i0 = blockIdx.x * 256;
    const int o0 = blockIdx.y * 64;
    const int t  = threadIdx.x;

    __shared__ float As[LORA_RANK][256];
    __shared__ float Bs[64][LORA_RANK];

    #pragma unroll
    for (int j = 0; j < 16; ++j) {
        int idx = t + j * 256;
        int r = idx >> 8, c = idx & 255;
        As[r][c] = lA[(long)r * K + i0 + c];
    }
    #pragma unroll
    for (int j = 0; j < 4; ++j) {
        int idx = t + j * 256;
        int o = idx >> 4, r = idx & 15;
        Bs[o][r] = lB[(long)(o0 + o) * LORA_RANK + r] * SCALING;
    }
    __syncthreads();

    const int ol = t & 63;
    const int iq = t >> 6;
    const int o  = o0 + ol;

    float bb[LORA_RANK];
    #pragma unroll
    for (int r = 0; r < LORA_RANK; ++r) bb[r] = Bs[ol][r];

    __bf16* lrow = L + (long)o * K + i0 + iq * 64;
    #pragma unroll
    for (int c = 0; c < 16; ++c) {
        const int ib = iq * 64 + c * 4;
        f32x4 v = {0.f, 0.f, 0.f, 0.f};
        #pragma unroll
        for (int r = 0; r < LORA_RANK; ++r) {
            v[0] += bb[r] * As[r][ib + 0];
            v[1] += bb[r] * As[r][ib + 1];
            v[2] += bb[r] * As[r][ib + 2];
            v[3] += bb[r] * As[r][ib + 3];
        }
        bf16x4 wv;
        wv[0] = (__bf16)v[0]; wv[1] = (__bf16)v[1];
        wv[2] = (__bf16)v[2]; wv[3] = (__bf16)v[3];
        *(bf16x4*)(lrow + c * 4) = wv;
    }
}

// ---------------------------------------------------------------------------
// Per-output-row: W' = q*s + L; s' = rowmax/127; W8 = round(W'/s').  K==4096.
// ---------------------------------------------------------------------------
__global__ __launch_bounds__(256) void quant_w_kernel(
    const int* __restrict__ q, const float* __restrict__ scales,
    const __bf16* __restrict__ L, signed char* __restrict__ W8,
    float* __restrict__ sn, int K)
{
    const int o = blockIdx.x, t = threadIdx.x;
    const int lane = t & 63, wid = t >> 6;
    __shared__ float wm[4];

    const int4*   qr = (const int4*)(q + (long)o * K);
    const bf16x4* Lr = (const bf16x4*)(L + (long)o * K);
    const float   s  = scales[o];

    float w[16];
    float mx = 0.f;
    #pragma unroll
    for (int j = 0; j < 4; ++j) {
        int c = t + j * 256;
        int4   qv = qr[c];
        bf16x4 lv = Lr[c];
        w[4 * j + 0] = (float)qv.x * s + (float)lv[0];
        w[4 * j + 1] = (float)qv.y * s + (float)lv[1];
        w[4 * j + 2] = (float)qv.z * s + (float)lv[2];
        w[4 * j + 3] = (float)qv.w * s + (float)lv[3];
        mx = fmaxf(mx, fmaxf(fmaxf(fabsf(w[4 * j]), fabsf(w[4 * j + 1])),
                             fmaxf(fabsf(w[4 * j + 2]), fabsf(w[4 * j + 3]))));
    }
    #pragma unroll
    for (int off = 32; off; off >>= 1) mx = fmaxf(mx, __shfl_xor(mx, off));
    if (lane == 0) wm[wid] = mx;
    __syncthreads();
    const float gmax = fmaxf(fmaxf(fmaxf(wm[0], wm[1]), fmaxf(wm[2], wm[3])), 1e-30f);
    const float winv = 127.0f / gmax;

    int* wrow = (int*)(W8 + (long)o * K);
    #pragma unroll
    for (int j = 0; j < 4; ++j) {
        int c0 = (int)rintf(fminf(fmaxf(w[4 * j + 0] * winv, -127.f), 127.f));
        int c1 = (int)rintf(fminf(fmaxf(w[4 * j + 1] * winv, -127.f), 127.f));
        int c2 = (int)rintf(fminf(fmaxf(w[4 * j + 2] * winv, -127.f), 127.f));
        int c3 = (int)rintf(fminf(fmaxf(w[4 * j + 3] * winv, -127.f), 127.f));
        wrow[t + j * 256] = (c0 & 255) | ((c1 & 255) << 8) | ((c2 & 255) << 16) | (c3 << 24);
    }
    if (t == 0) sn[o] = gmax / 127.0f;
}

// ---------------------------------------------------------------------------
// Per-X-row: sx = rowmax|x|/127; X8 = round(x/sx).  K==4096.
// ---------------------------------------------------------------------------
__global__ __launch_bounds__(256) void quant_x_kernel(
    const float* __restrict__ X, signed char* __restrict__ X8,
    float* __restrict__ sxm, int K)
{
    const int m = blockIdx.x, t = threadIdx.x;
    const int lane = t & 63, wid = t >> 6;
    __shared__ float wm[4];

    const f32x4* xr = (const f32x4*)(X + (long)m * K);
    f32x4 v[4];
    float mx = 0.f;
    #pragma unroll
    for (int j = 0; j < 4; ++j) {
        v[j] = xr[t + j * 256];
        mx = fmaxf(mx, fmaxf(fmaxf(fabsf(v[j][0]), fabsf(v[j][1])),
                             fmaxf(fabsf(v[j][2]), fabsf(v[j][3]))));
    }
    #pragma unroll
    for (int off = 32; off; off >>= 1) mx = fmaxf(mx, __shfl_xor(mx, off));
    if (lane == 0) wm[wid] = mx;
    __syncthreads();
    const float gmax = fmaxf(fmaxf(fmaxf(wm[0], wm[1]), fmaxf(wm[2], wm[3])), 1e-30f);
    const float xinv = 127.0f / gmax;

    int* xrow = (int*)(X8 + (long)m * K);
    #pragma unroll
    for (int j = 0; j < 4; ++j) {
        int c0 = (int)rintf(fminf(fmaxf(v[j][0] * xinv, -127.f), 127.f));
        int c1 = (int)rintf(fminf(fmaxf(v[j][1] * xinv, -127.f), 127.f));
        int c2 = (int)rintf(fminf(fmaxf(v[j][2] * xinv, -127.f), 127.f));
        int c3 = (int)rintf(fminf(fmaxf(v[j][3] * xinv, -127.f), 127.f));
        xrow[t + j * 256] = (c0 & 255) | ((c1 & 255) << 8) | ((c2 & 255) << 16) | (c3 << 24);
    }
    if (t == 0) sxm[m] = gmax / 127.0f;
}

// ---------------------------------------------------------------------------
// INT8 GEMM, occupancy experiment: 128x128 tile, 256 thr (4 waves 2x2,
// per-wave 64x64 -> acc only 64 AGPR), BK=128, single-buffer LDS 32KB,
// __launch_bounds__(256,3) -> 3 blocks/CU. Cross-BLOCK overlap (m114) feeds
// the MFMA pipe while other blocks stage/read — the lever the 1-block/CU
// 256^2 structure couldn't reach. Same verified 128B-row XOR swizzle.
// ---------------------------------------------------------------------------
#define VMW0  asm volatile("s_waitcnt vmcnt(0)" ::: "memory")
#define SB0   __builtin_amdgcn_sched_barrier(0)

#define RD4(base, off) (*(const i32x4*)((base) + (off)))

#define MFI(mi, nj, A, B) \
    acc[mi][nj] = __builtin_amdgcn_mfma_i32_16x16x64_i8(A, B, acc[mi][nj], 0, 0, 0)

// stage A(16KB)+B(16KB): 8 rounds of 4KB (256 thr x 16B); 32 rows per round
#define STAGE_S(dA, dB) do { \
    __builtin_amdgcn_global_load_lds(GLB(pB),           LDS((dB) + wb),         16, 0, 0); \
    __builtin_amdgcn_global_load_lds(GLB(pB + rk32),    LDS((dB) + wb +  4096), 16, 0, 0); \
    __builtin_amdgcn_global_load_lds(GLB(pB + 2*rk32),  LDS((dB) + wb +  8192), 16, 0, 0); \
    __builtin_amdgcn_global_load_lds(GLB(pB + 3*rk32),  LDS((dB) + wb + 12288), 16, 0, 0); \
    __builtin_amdgcn_global_load_lds(GLB(pA),           LDS((dA) + wb),         16, 0, 0); \
    __builtin_amdgcn_global_load_lds(GLB(pA + rk32),    LDS((dA) + wb +  4096), 16, 0, 0); \
    __builtin_amdgcn_global_load_lds(GLB(pA + 2*rk32),  LDS((dA) + wb +  8192), 16, 0, 0); \
    __builtin_amdgcn_global_load_lds(GLB(pA + 3*rk32),  LDS((dA) + wb + 12288), 16, 0, 0); } while (0)

__global__ __launch_bounds__(256, 3) void gemm_i8_kernel(
    const signed char* __restrict__ X8, const signed char* __restrict__ W8,
    const float* __restrict__ sxm, const float* __restrict__ sn,
    const float* __restrict__ bias, float* __restrict__ C,
    int M, int N, int K)
{
    // single buffer: A [0,16K) B [16K,32K)
    __shared__ __align__(16) char smem[32768];

    const int t = threadIdx.x, wid = t >> 6, lane = t & 63;
    const int wr = wid >> 1, wc = wid & 1;
    const int l15 = lane & 15, l7 = lane & 7, lk = lane >> 4;

    const int nwg = gridDim.x;
    int bid = blockIdx.x;
    if ((nwg & 7) == 0) bid = (bid & 7) * (nwg >> 3) + (bid >> 3);
    const int ntn = N >> 7;
    const int m0 = (bid / ntn) << 7, n0 = (bid % ntn) << 7;

    // staging: thread t covers row sr = t>>3 (0..31) per 32-row round,
    // source chunk pre-swizzled: ch = (t&7)^(sr&7)  (rule #21).
    const int sr = t >> 3;
    const int ch = (t & 7) ^ (sr & 7);
    const long rk32 = 32L * K;                     // 32-row stride (bytes)
    const signed char* pA = X8 + (long)(m0 + sr) * K + ch * 16;
    const signed char* pB = W8 + (long)(n0 + sr) * K + ch * 16;

    const int wb = wid * 1024;                     // wave-uniform stage base

    // fragment reads: row base+l15 (+16*i), k-chunk (lk + 4*ks) ^ (row&7)
    const int aRow = (wr * 64 + l15) * 128;
    const int bRow = (wc * 64 + l15) * 128;
    const int kc0  = ((lk    ) ^ l7) << 4;
    const int kc1  = ((lk + 4) ^ l7) << 4;

    char* const bA = smem;
    char* const bB = smem + 16384;

    i32x4 acc[4][4] = {};

    const int nkt = K >> 7;                        // BK = 128

    STAGE_S(bA, bB);
    pA += 128; pB += 128;

    for (int kt = 0; kt < nkt; ++kt) {
        VMW0;                                      // staged tile visible
        __builtin_amdgcn_s_barrier();
        SB0;
        __builtin_amdgcn_s_setprio(1);
        { // k-slice 0
            i32x4 b0 = RD4(bB, bRow +    0 + kc0);
            i32x4 b1 = RD4(bB, bRow + 2048 + kc0);
            i32x4 b2 = RD4(bB, bRow + 4096 + kc0);
            i32x4 b3 = RD4(bB, bRow + 6144 + kc0);
            i32x4 a0 = RD4(bA, aRow +    0 + kc0);
            i32x4 a1 = RD4(bA, aRow + 2048 + kc0);
            i32x4 a2 = RD4(bA, aRow + 4096 + kc0);
            i32x4 a3 = RD4(bA, aRow + 6144 + kc0);
            MFI(0,0,a0,b0); MFI(1,0,a1,b0); MFI(2,0,a2,b0); MFI(3,0,a3,b0);
            MFI(0,1,a0,b1); MFI(1,1,a1,b1); MFI(2,1,a2,b1); MFI(3,1,a3,b1);
            MFI(0,2,a0,b2); MFI(1,2,a1,b2); MFI(2,2,a2,b2); MFI(3,2,a3,b2);
            MFI(0,3,a0,b3); MFI(1,3,a1,b3); MFI(2,3,a2,b3); MFI(3,3,a3,b3);
        }
        { // k-slice 1
            i32x4 b0 = RD4(bB, bRow +    0 + kc1);
            i32x4 b1 = RD4(bB, bRow + 2048 + kc1);
            i32x4 b2 = RD4(bB, bRow + 4096 + kc1);
            i32x4 b3 = RD4(bB, bRow + 6144 + kc1);
            i32x4 a0 = RD4(bA, aRow +    0 + kc1);
            i32x4 a1 = RD4(bA, aRow + 2048 + kc1);
            i32x4 a2 = RD4(bA, aRow + 4096 + kc1);
            i32x4 a3 = RD4(bA, aRow + 6144 + kc1);
            MFI(0,0,a0,b0); MFI(1,0,a1,b0); MFI(2,0,a2,b0); MFI(3,0,a3,b0);
            MFI(0,1,a0,b1); MFI(1,1,a1,b1); MFI(2,1,a2,b1); MFI(3,1,a3,b1);
            MFI(0,2,a0,b2); MFI(1,2,a1,b2); MFI(2,2,a2,b2); MFI(3,2,a3,b2);
            MFI(0,3,a0,b3); MFI(1,3,a1,b3); MFI(2,3,a2,b3); MFI(3,3,a3,b3);
        }
        __builtin_amdgcn_s_setprio(0);
        asm volatile("s_waitcnt lgkmcnt(0)" ::: "memory");  // my reads done
        __builtin_amdgcn_s_barrier();              // all waves done reading
        SB0;
        if (kt + 1 < nkt) {
            STAGE_S(bA, bB);                       // overwrite with next tile
            pA += 128; pB += 128;
        }
    }

    // epilogue: col = lane&15 (+nj*16), row = (lane>>4)*4 + e (+mi*16)
    #pragma unroll
    for (int nj = 0; nj < 4; ++nj) {
        const int col = n0 + wc * 64 + nj * 16 + l15;
        const float scol = sn[col];
        const float bv   = bias[col];
        #pragma unroll
        for (int mi = 0; mi < 4; ++mi) {
            const long rowb = (long)m0 + wr * 64 + mi * 16 + (lane >> 4) * 4;
            const f32x4 sx4 = *(const f32x4*)(sxm + rowb);
            float* Cp = C + rowb * N + col;
            Cp[0]       = (float)acc[mi][nj][0] * (sx4[0] * scol) + bv;
            Cp[(long)N] = (float)acc[mi][nj][1] * (sx4[1] * scol) + bv;
            Cp[2L * N]  = (float)acc[mi][nj][2] * (sx4[2] * scol) + bv;
            Cp[3L * N]  = (float)acc[mi][nj][3] * (sx4[3] * scol) + bv;
        }
    }
}

// ---------------------------------------------------------------------------
// Last-resort fallback: on-the-fly dequant+LoRA fp32 GEMM (odd shapes / no ws).
// ---------------------------------------------------------------------------
__global__ __launch_bounds__(256) void fallback_gemm(
    const float* __restrict__ X, const int* __restrict__ q,
    const float* __restrict__ scales, const float* __restrict__ bias,
    const float* __restrict__ lA, const float* __restrict__ lB,
    float* __restrict__ C, int M, int N, int K)
{
    __shared__ float Xs[64][17];
    __shared__ float Ws[64][17];
    __shared__ float At[LORA_RANK][16];
    __shared__ float Bt[64][LORA_RANK];

    const int ntn = N >> 6;
    const int m0 = (blockIdx.x / ntn) << 6, n0 = (blockIdx.x % ntn) << 6;
    const int t = threadIdx.x;

    for (int j = t; j < 64 * LORA_RANK; j += 256)
        Bt[j >> 4][j & 15] = lB[(long)(n0 + (j >> 4)) * LORA_RANK + (j & 15)] * SCALING;

    const int tr = (t & 15) * 4, tc = (t >> 4) * 4;
    float acc[4][4] = {};

    for (int k0 = 0; k0 < K; k0 += 16) {
        __syncthreads();
        for (int j = t; j < 1024; j += 256)
            Xs[j >> 4][j & 15] = X[(long)(m0 + (j >> 4)) * K + k0 + (j & 15)];
        At[t >> 4][t & 15] = lA[(long)(t >> 4) * K + k0 + (t & 15)];
        __syncthreads();
        for (int j = t; j < 1024; j += 256) {
            int o = j >> 4, kk = j & 15;
            float v = (float)q[(long)(n0 + o) * K + k0 + kk] * scales[n0 + o];
            #pragma unroll
            for (int r = 0; r < LORA_RANK; ++r) v += Bt[o][r] * At[r][kk];
            Ws[o][kk] = v;
        }
        __syncthreads();
        #pragma unroll 4
        for (int kk = 0; kk < 16; ++kk)
            #pragma unroll
            for (int i = 0; i < 4; ++i)
                #pragma unroll
                for (int j = 0; j < 4; ++j)
                    acc[i][j] += Xs[tr + i][kk] * Ws[tc + j][kk];
    }
    __syncthreads();
    #pragma unroll
    for (int i = 0; i < 4; ++i)
        #pragma unroll
        for (int j = 0; j < 4; ++j)
            C[(long)(m0 + tr + i) * N + n0 + tc + j] = acc[i][j] + bias[n0 + tc + j];
}

// ---------------------------------------------------------------------------
extern "C" void kernel_launch(void* const* d_in, const int* in_sizes, int n_in,
                              void* d_out, int out_size, void* d_ws, size_t ws_size,
                              hipStream_t stream)
{
    const float* x      = (const float*)d_in[0];
    const int*   qw     = (const int*)d_in[1];
    const float* scales = (const float*)d_in[2];
    const float* bias   = (const float*)d_in[3];
    const float* lA     = (const float*)d_in[4];
    const float* lB     = (const float*)d_in[5];
    float*       out    = (float*)d_out;

    const int K = in_sizes[4] / LORA_RANK;   // 4096
    const int N = in_sizes[2];               // 4096
    const int M = in_sizes[0] / K;           // 8192

    const size_t i8need = (size_t)N * K + (size_t)M * K + (size_t)(M + N) * 4
                        + (size_t)N * K * 2 + 256;
    const bool i8_ok = (K == 4096) && (M % 128) == 0 && (N % 128) == 0 &&
                       (K % 256) == 0 && (N % 64) == 0 && ws_size >= i8need;

    if (i8_ok) {
        signed char* W8  = (signed char*)d_ws;
        signed char* X8  = W8 + (size_t)N * K;
        float*       sxm = (float*)(X8 + (size_t)M * K);
        float*       sn  = sxm + M;
        __bf16*      L   = (__bf16*)(sn + N);

        dim3 g1(K / 256, N / 64);
        lora_mat_kernel<<<g1, 256, 0, stream>>>(lA, lB, L, N, K);
        quant_w_kernel<<<N, 256, 0, stream>>>(qw, scales, L, W8, sn, K);
        quant_x_kernel<<<M, 256, 0, stream>>>(x, X8, sxm, K);
        const int nwg = (M / 128) * (N / 128);
        gemm_i8_kernel<<<nwg, 256, 0, stream>>>(X8, W8, sxm, sn, bias, out, M, N, K);
    } else {
        fallback_gemm<<<(M / 64) * (N / 64), 256, 0, stream>>>(
            x, qw, scales, bias, lA, lB, out, M, N, K);
    }
}

// Round 18
// 230.018 us; speedup vs baseline: 1.0318x; 1.0318x over previous
//
#include <hip/hip_runtime.h>

#define LORA_RANK 16
#define SCALING 2.0f

using bf16x8 = __attribute__((ext_vector_type(8))) __bf16;
using bf16x4 = __attribute__((ext_vector_type(4))) __bf16;
using f32x4  = __attribute__((ext_vector_type(4))) float;
using i32x4  = __attribute__((ext_vector_type(4))) int;
using i32x16 = __attribute__((ext_vector_type(16))) int;

#define GLB(p) ((const __attribute__((address_space(1))) void*)(p))
#define LDS(p) ((__attribute__((address_space(3))) void*)(p))

// ---------------------------------------------------------------------------
// L[o][i] = SCALING * sum_r lB[o][r]*lA[r][i]  -> bf16 into d_ws scratch.
// ---------------------------------------------------------------------------
__global__ __launch_bounds__(256) void lora_mat_kernel(
    const float* __restrict__ lA, const float* __restrict__ lB,
    __bf16* __restrict__ L, int N, int K)
{
    const int i0 = blockIdx.x * 256;
    const int o0 = blockIdx.y * 64;
    const int t  = threadIdx.x;

    __shared__ float As[LORA_RANK][256];
    __shared__ float Bs[64][LORA_RANK];

    #pragma unroll
    for (int j = 0; j < 16; ++j) {
        int idx = t + j * 256;
        int r = idx >> 8, c = idx & 255;
        As[r][c] = lA[(long)r * K + i0 + c];
    }
    #pragma unroll
    for (int j = 0; j < 4; ++j) {
        int idx = t + j * 256;
        int o = idx >> 4, r = idx & 15;
        Bs[o][r] = lB[(long)(o0 + o) * LORA_RANK + r] * SCALING;
    }
    __syncthreads();

    const int ol = t & 63;
    const int iq = t >> 6;
    const int o  = o0 + ol;

    float bb[LORA_RANK];
    #pragma unroll
    for (int r = 0; r < LORA_RANK; ++r) bb[r] = Bs[ol][r];

    __bf16* lrow = L + (long)o * K + i0 + iq * 64;
    #pragma unroll
    for (int c = 0; c < 16; ++c) {
        const int ib = iq * 64 + c * 4;
        f32x4 v = {0.f, 0.f, 0.f, 0.f};
        #pragma unroll
        for (int r = 0; r < LORA_RANK; ++r) {
            v[0] += bb[r] * As[r][ib + 0];
            v[1] += bb[r] * As[r][ib + 1];
            v[2] += bb[r] * As[r][ib + 2];
            v[3] += bb[r] * As[r][ib + 3];
        }
        bf16x4 wv;
        wv[0] = (__bf16)v[0]; wv[1] = (__bf16)v[1];
        wv[2] = (__bf16)v[2]; wv[3] = (__bf16)v[3];
        *(bf16x4*)(lrow + c * 4) = wv;
    }
}

// ---------------------------------------------------------------------------
// Per-output-row: W' = q*s + L; s' = rowmax/127; W8 = round(W'/s').  K==4096.
// ---------------------------------------------------------------------------
__global__ __launch_bounds__(256) void quant_w_kernel(
    const int* __restrict__ q, const float* __restrict__ scales,
    const __bf16* __restrict__ L, signed char* __restrict__ W8,
    float* __restrict__ sn, int K)
{
    const int o = blockIdx.x, t = threadIdx.x;
    const int lane = t & 63, wid = t >> 6;
    __shared__ float wm[4];

    const int4*   qr = (const int4*)(q + (long)o * K);
    const bf16x4* Lr = (const bf16x4*)(L + (long)o * K);
    const float   s  = scales[o];

    float w[16];
    float mx = 0.f;
    #pragma unroll
    for (int j = 0; j < 4; ++j) {
        int c = t + j * 256;
        int4   qv = qr[c];
        bf16x4 lv = Lr[c];
        w[4 * j + 0] = (float)qv.x * s + (float)lv[0];
        w[4 * j + 1] = (float)qv.y * s + (float)lv[1];
        w[4 * j + 2] = (float)qv.z * s + (float)lv[2];
        w[4 * j + 3] = (float)qv.w * s + (float)lv[3];
        mx = fmaxf(mx, fmaxf(fmaxf(fabsf(w[4 * j]), fabsf(w[4 * j + 1])),
                             fmaxf(fabsf(w[4 * j + 2]), fabsf(w[4 * j + 3]))));
    }
    #pragma unroll
    for (int off = 32; off; off >>= 1) mx = fmaxf(mx, __shfl_xor(mx, off));
    if (lane == 0) wm[wid] = mx;
    __syncthreads();
    const float gmax = fmaxf(fmaxf(fmaxf(wm[0], wm[1]), fmaxf(wm[2], wm[3])), 1e-30f);
    const float winv = 127.0f / gmax;

    int* wrow = (int*)(W8 + (long)o * K);
    #pragma unroll
    for (int j = 0; j < 4; ++j) {
        int c0 = (int)rintf(fminf(fmaxf(w[4 * j + 0] * winv, -127.f), 127.f));
        int c1 = (int)rintf(fminf(fmaxf(w[4 * j + 1] * winv, -127.f), 127.f));
        int c2 = (int)rintf(fminf(fmaxf(w[4 * j + 2] * winv, -127.f), 127.f));
        int c3 = (int)rintf(fminf(fmaxf(w[4 * j + 3] * winv, -127.f), 127.f));
        wrow[t + j * 256] = (c0 & 255) | ((c1 & 255) << 8) | ((c2 & 255) << 16) | (c3 << 24);
    }
    if (t == 0) sn[o] = gmax / 127.0f;
}

// ---------------------------------------------------------------------------
// Per-X-row: sx = rowmax|x|/127; X8 = round(x/sx).  K==4096.
// ---------------------------------------------------------------------------
__global__ __launch_bounds__(256) void quant_x_kernel(
    const float* __restrict__ X, signed char* __restrict__ X8,
    float* __restrict__ sxm, int K)
{
    const int m = blockIdx.x, t = threadIdx.x;
    const int lane = t & 63, wid = t >> 6;
    __shared__ float wm[4];

    const f32x4* xr = (const f32x4*)(X + (long)m * K);
    f32x4 v[4];
    float mx = 0.f;
    #pragma unroll
    for (int j = 0; j < 4; ++j) {
        v[j] = xr[t + j * 256];
        mx = fmaxf(mx, fmaxf(fmaxf(fabsf(v[j][0]), fabsf(v[j][1])),
                             fmaxf(fabsf(v[j][2]), fabsf(v[j][3]))));
    }
    #pragma unroll
    for (int off = 32; off; off >>= 1) mx = fmaxf(mx, __shfl_xor(mx, off));
    if (lane == 0) wm[wid] = mx;
    __syncthreads();
    const float gmax = fmaxf(fmaxf(fmaxf(wm[0], wm[1]), fmaxf(wm[2], wm[3])), 1e-30f);
    const float xinv = 127.0f / gmax;

    int* xrow = (int*)(X8 + (long)m * K);
    #pragma unroll
    for (int j = 0; j < 4; ++j) {
        int c0 = (int)rintf(fminf(fmaxf(v[j][0] * xinv, -127.f), 127.f));
        int c1 = (int)rintf(fminf(fmaxf(v[j][1] * xinv, -127.f), 127.f));
        int c2 = (int)rintf(fminf(fmaxf(v[j][2] * xinv, -127.f), 127.f));
        int c3 = (int)rintf(fminf(fmaxf(v[j][3] * xinv, -127.f), 127.f));
        xrow[t + j * 256] = (c0 & 255) | ((c1 & 255) << 8) | ((c2 & 255) << 16) | (c3 << 24);
    }
    if (t == 0) sxm[m] = gmax / 127.0f;
}

// ---------------------------------------------------------------------------
// INT8 GEMM with mfma_i32_32x32x32_i8: 256x256 tile, BK=128, 128B rows +
// 8-chunk XOR swizzle. Same LDS traffic as champion (24 b128/wave/tile, all
// at the 1KB/instr floor), but 2x MACs/MFMA -> 32 MFMA/wave/tile at the
// 4404-TOPS 32x32 rate (+11.7% pipe). 8 waves (2Mx4N), per-wave 128x64 out
// = 4x2 C-tiles x 16 AGPR. 1 barrier + 1 vmcnt per K-tile, dbuf 128KB.
// C/D layout: col=lane&31, row=(reg&3)+8*(reg>>2)+4*(lane>>5)  [m74/m101].
// A/B layout: row/col=lane&31, 16B k-half = lane>>5.
// ---------------------------------------------------------------------------
#define VMW0  asm volatile("s_waitcnt vmcnt(0)" ::: "memory")
#define SB0   __builtin_amdgcn_sched_barrier(0)
#define SGB(mask, n) __builtin_amdgcn_sched_group_barrier((mask), (n), 0)

#define RD4(base, off) (*(const i32x4*)((base) + (off)))

#define MFI32(mi, nj, A, B) \
    acc[mi][nj] = __builtin_amdgcn_mfma_i32_32x32x32_i8(A, B, acc[mi][nj], 0, 0, 0)

// stage one 256x128B operand (32KB) = 4 rounds of 8KB (512 thr x 16B)
#define STAGE_I8(dA, dB) do { \
    __builtin_amdgcn_global_load_lds(GLB(pB),          LDS((dB) + wb),         16, 0, 0); \
    __builtin_amdgcn_global_load_lds(GLB(pB + rk),     LDS((dB) + wb +  8192), 16, 0, 0); \
    __builtin_amdgcn_global_load_lds(GLB(pB + 2 * rk), LDS((dB) + wb + 16384), 16, 0, 0); \
    __builtin_amdgcn_global_load_lds(GLB(pB + 3 * rk), LDS((dB) + wb + 24576), 16, 0, 0); \
    __builtin_amdgcn_global_load_lds(GLB(pA),          LDS((dA) + wb),         16, 0, 0); \
    __builtin_amdgcn_global_load_lds(GLB(pA + rk),     LDS((dA) + wb +  8192), 16, 0, 0); \
    __builtin_amdgcn_global_load_lds(GLB(pA + 2 * rk), LDS((dA) + wb + 16384), 16, 0, 0); \
    __builtin_amdgcn_global_load_lds(GLB(pA + 3 * rk), LDS((dA) + wb + 24576), 16, 0, 0); } while (0)

#define ADVP8(a) do { pA += (a); pB += (a); } while (0)

// One k-step (32 of K): 4 A-tiles + 2 B-tiles read, 8 MFMAs.
#define KSTEP(kcs) do { \
    i32x4 a0 = RD4(_ac, aRow0 +     0 + (kcs)); \
    i32x4 a1 = RD4(_ac, aRow0 +  4096 + (kcs)); \
    i32x4 a2 = RD4(_ac, aRow0 +  8192 + (kcs)); \
    i32x4 a3 = RD4(_ac, aRow0 + 12288 + (kcs)); \
    i32x4 b0 = RD4(_bc, bRow0 +     0 + (kcs)); \
    i32x4 b1 = RD4(_bc, bRow0 +  4096 + (kcs)); \
    MFI32(0,0,a0,b0); MFI32(1,0,a1,b0); MFI32(2,0,a2,b0); MFI32(3,0,a3,b0); \
    MFI32(0,1,a0,b1); MFI32(1,1,a1,b1); MFI32(2,1,a2,b1); MFI32(3,1,a3,b1); } while (0)

// One K-tile (BK=128 = 4 k-steps of 32), no internal barriers.
#define TILE32(Ac, Bc, DOSTAGE) do { \
    const char* _ac = (Ac); const char* _bc = (Bc); \
    DOSTAGE; \
    __builtin_amdgcn_s_setprio(1); \
    KSTEP(kcs0); \
    KSTEP(kcs1); \
    KSTEP(kcs2); \
    KSTEP(kcs3); \
    SGB(0x30, 8); \
    SGB(0x100, 6); \
    SGB(0x8, 8); SGB(0x100, 6); \
    SGB(0x8, 8); SGB(0x100, 6); \
    SGB(0x8, 8); SGB(0x100, 6); \
    SGB(0x8, 8); \
    __builtin_amdgcn_s_setprio(0); \
    VMW0; \
    __builtin_amdgcn_s_barrier(); \
    SB0; \
  } while (0)

__global__ __launch_bounds__(512, 2) void gemm_i8_kernel(
    const signed char* __restrict__ X8, const signed char* __restrict__ W8,
    const float* __restrict__ sxm, const float* __restrict__ sn,
    const float* __restrict__ bias, float* __restrict__ C,
    int M, int N, int K)
{
    // buf0 A [0,32K) B [32K,64K) | buf1 A [64K,96K) B [96K,128K)
    __shared__ __align__(16) char smem[131072];

    const int t = threadIdx.x, wid = t >> 6, lane = t & 63;
    const int wr = wid >> 2, wc = wid & 3;
    const int l31 = lane & 31, l7 = lane & 7, lh = lane >> 5;

    const int nwg = gridDim.x;
    int bid = blockIdx.x;
    if ((nwg & 7) == 0) bid = (bid & 7) * (nwg >> 3) + (bid >> 3);
    const int ntn = N >> 8;
    const int m0 = (bid / ntn) << 8, n0 = (bid % ntn) << 8;

    // staging: thread t sources row (t>>3)+64k, chunk (t&7)^((t>>3)&7)
    const int sr = t >> 3;
    const int ch = (t & 7) ^ (sr & 7);
    const long rk = 64L * K;                       // 64-row stride in bytes
    const signed char* pA = X8 + (long)(m0 + sr) * K + ch * 16;
    const signed char* pB = W8 + (long)(n0 + sr) * K + ch * 16;

    const int wb = wid * 1024;                     // wave-uniform stage base

    // fragment reads: row base + l31 (+32*mi), k-chunk (2*ks + lh) ^ (row&7)
    const int aRow0 = (wr * 128 + l31) * 128;
    const int bRow0 = (wc * 64  + l31) * 128;
    const int kcs0  = ((0 + lh) ^ l7) << 4;
    const int kcs1  = ((2 + lh) ^ l7) << 4;
    const int kcs2  = ((4 + lh) ^ l7) << 4;
    const int kcs3  = ((6 + lh) ^ l7) << 4;

    char* const bA0 = smem;
    char* const bB0 = smem + 32768;
    char* const bA1 = smem + 65536;
    char* const bB1 = smem + 98304;

    i32x16 acc[4][2] = {};

    const int nkt = K >> 7;                        // BK = 128

    STAGE_I8(bA0, bB0);
    ADVP8(nkt > 1 ? 128 : 0);
    VMW0;
    __builtin_amdgcn_s_barrier();
    SB0;

    for (int kt = 0; kt < nkt; kt += 2) {
        const long adv1 = (kt + 2 < nkt) ? 128 : 0;
        const long adv2 = (kt + 3 < nkt) ? 128 : 0;
        TILE32(bA0, bB0, { STAGE_I8(bA1, bB1); ADVP8(adv1); });
        TILE32(bA1, bB1, { STAGE_I8(bA0, bB0); ADVP8(adv2); });
    }

    // epilogue: col = lane&31 (+nj*32); row = (reg&3)+8*(reg>>2)+4*lh (+mi*32)
    #pragma unroll
    for (int nj = 0; nj < 2; ++nj) {
        const int col = n0 + wc * 64 + nj * 32 + l31;
        const float scol = sn[col];
        const float bv   = bias[col];
        #pragma unroll
        for (int mi = 0; mi < 4; ++mi) {
            const long base = (long)m0 + wr * 128 + mi * 32 + 4 * lh;
            #pragma unroll
            for (int qq = 0; qq < 4; ++qq) {
                const long rowq = base + 8 * qq;
                const f32x4 sx4 = *(const f32x4*)(sxm + rowq);
                float* Cp = C + rowq * N + col;
                Cp[0]       = (float)acc[mi][nj][4 * qq + 0] * (sx4[0] * scol) + bv;
                Cp[(long)N] = (float)acc[mi][nj][4 * qq + 1] * (sx4[1] * scol) + bv;
                Cp[2L * N]  = (float)acc[mi][nj][4 * qq + 2] * (sx4[2] * scol) + bv;
                Cp[3L * N]  = (float)acc[mi][nj][4 * qq + 3] * (sx4[3] * scol) + bv;
            }
        }
    }
}

// ---------------------------------------------------------------------------
// Last-resort fallback: on-the-fly dequant+LoRA fp32 GEMM (odd shapes / no ws).
// ---------------------------------------------------------------------------
__global__ __launch_bounds__(256) void fallback_gemm(
    const float* __restrict__ X, const int* __restrict__ q,
    const float* __restrict__ scales, const float* __restrict__ bias,
    const float* __restrict__ lA, const float* __restrict__ lB,
    float* __restrict__ C, int M, int N, int K)
{
    __shared__ float Xs[64][17];
    __shared__ float Ws[64][17];
    __shared__ float At[LORA_RANK][16];
    __shared__ float Bt[64][LORA_RANK];

    const int ntn = N >> 6;
    const int m0 = (blockIdx.x / ntn) << 6, n0 = (blockIdx.x % ntn) << 6;
    const int t = threadIdx.x;

    for (int j = t; j < 64 * LORA_RANK; j += 256)
        Bt[j >> 4][j & 15] = lB[(long)(n0 + (j >> 4)) * LORA_RANK + (j & 15)] * SCALING;

    const int tr = (t & 15) * 4, tc = (t >> 4) * 4;
    float acc[4][4] = {};

    for (int k0 = 0; k0 < K; k0 += 16) {
        __syncthreads();
        for (int j = t; j < 1024; j += 256)
            Xs[j >> 4][j & 15] = X[(long)(m0 + (j >> 4)) * K + k0 + (j & 15)];
        At[t >> 4][t & 15] = lA[(long)(t >> 4) * K + k0 + (t & 15)];
        __syncthreads();
        for (int j = t; j < 1024; j += 256) {
            int o = j >> 4, kk = j & 15;
            float v = (float)q[(long)(n0 + o) * K + k0 + kk] * scales[n0 + o];
            #pragma unroll
            for (int r = 0; r < LORA_RANK; ++r) v += Bt[o][r] * At[r][kk];
            Ws[o][kk] = v;
        }
        __syncthreads();
        #pragma unroll 4
        for (int kk = 0; kk < 16; ++kk)
            #pragma unroll
            for (int i = 0; i < 4; ++i)
                #pragma unroll
                for (int j = 0; j < 4; ++j)
                    acc[i][j] += Xs[tr + i][kk] * Ws[tc + j][kk];
    }
    __syncthreads();
    #pragma unroll
    for (int i = 0; i < 4; ++i)
        #pragma unroll
        for (int j = 0; j < 4; ++j)
            C[(long)(m0 + tr + i) * N + n0 + tc + j] = acc[i][j] + bias[n0 + tc + j];
}

// ---------------------------------------------------------------------------
extern "C" void kernel_launch(void* const* d_in, const int* in_sizes, int n_in,
                              void* d_out, int out_size, void* d_ws, size_t ws_size,
                              hipStream_t stream)
{
    const float* x      = (const float*)d_in[0];
    const int*   qw     = (const int*)d_in[1];
    const float* scales = (const float*)d_in[2];
    const float* bias   = (const float*)d_in[3];
    const float* lA     = (const float*)d_in[4];
    const float* lB     = (const float*)d_in[5];
    float*       out    = (float*)d_out;

    const int K = in_sizes[4] / LORA_RANK;   // 4096
    const int N = in_sizes[2];               // 4096
    const int M = in_sizes[0] / K;           // 8192

    const size_t i8need = (size_t)N * K + (size_t)M * K + (size_t)(M + N) * 4
                        + (size_t)N * K * 2 + 256;
    const bool i8_ok = (K == 4096) && (M % 256) == 0 && (N % 256) == 0 &&
                       ws_size >= i8need;

    if (i8_ok) {
        signed char* W8  = (signed char*)d_ws;
        signed char* X8  = W8 + (size_t)N * K;
        float*       sxm = (float*)(X8 + (size_t)M * K);
        float*       sn  = sxm + M;
        __bf16*      L   = (__bf16*)(sn + N);

        dim3 g1(K / 256, N / 64);
        lora_mat_kernel<<<g1, 256, 0, stream>>>(lA, lB, L, N, K);
        quant_w_kernel<<<N, 256, 0, stream>>>(qw, scales, L, W8, sn, K);
        quant_x_kernel<<<M, 256, 0, stream>>>(x, X8, sxm, K);
        const int nwg = (M / 256) * (N / 256);
        gemm_i8_kernel<<<nwg, 512, 0, stream>>>(X8, W8, sxm, sn, bias, out, M, N, K);
    } else {
        fallback_gemm<<<(M / 64) * (N / 64), 256, 0, stream>>>(
            x, qw, scales, bias, lA, lB, out, M, N, K);
    }
}

// Round 19
// 218.679 us; speedup vs baseline: 1.0853x; 1.0519x over previous
//
#include <hip/hip_runtime.h>

#define LORA_RANK 16
#define SCALING 2.0f

using bf16x8 = __attribute__((ext_vector_type(8))) __bf16;
using bf16x4 = __attribute__((ext_vector_type(4))) __bf16;
using f32x4  = __attribute__((ext_vector_type(4))) float;
using i32x4  = __attribute__((ext_vector_type(4))) int;

#define GLB(p) ((const __attribute__((address_space(1))) void*)(p))
#define LDS(p) ((__attribute__((address_space(3))) void*)(p))

// ---------------------------------------------------------------------------
// L[o][i] = SCALING * sum_r lB[o][r]*lA[r][i]  -> bf16 into d_ws scratch.
// ---------------------------------------------------------------------------
__global__ __launch_bounds__(256) void lora_mat_kernel(
    const float* __restrict__ lA, const float* __restrict__ lB,
    __bf16* __restrict__ L, int N, int K)
{
    const int i0 = blockIdx.x * 256;
    const int o0 = blockIdx.y * 64;
    const int t  = threadIdx.x;

    __shared__ float As[LORA_RANK][256];
    __shared__ float Bs[64][LORA_RANK];

    #pragma unroll
    for (int j = 0; j < 16; ++j) {
        int idx = t + j * 256;
        int r = idx >> 8, c = idx & 255;
        As[r][c] = lA[(long)r * K + i0 + c];
    }
    #pragma unroll
    for (int j = 0; j < 4; ++j) {
        int idx = t + j * 256;
        int o = idx >> 4, r = idx & 15;
        Bs[o][r] = lB[(long)(o0 + o) * LORA_RANK + r] * SCALING;
    }
    __syncthreads();

    const int ol = t & 63;
    const int iq = t >> 6;
    const int o  = o0 + ol;

    float bb[LORA_RANK];
    #pragma unroll
    for (int r = 0; r < LORA_RANK; ++r) bb[r] = Bs[ol][r];

    __bf16* lrow = L + (long)o * K + i0 + iq * 64;
    #pragma unroll
    for (int c = 0; c < 16; ++c) {
        const int ib = iq * 64 + c * 4;
        f32x4 v = {0.f, 0.f, 0.f, 0.f};
        #pragma unroll
        for (int r = 0; r < LORA_RANK; ++r) {
            v[0] += bb[r] * As[r][ib + 0];
            v[1] += bb[r] * As[r][ib + 1];
            v[2] += bb[r] * As[r][ib + 2];
            v[3] += bb[r] * As[r][ib + 3];
        }
        bf16x4 wv;
        wv[0] = (__bf16)v[0]; wv[1] = (__bf16)v[1];
        wv[2] = (__bf16)v[2]; wv[3] = (__bf16)v[3];
        *(bf16x4*)(lrow + c * 4) = wv;
    }
}

// ---------------------------------------------------------------------------
// Per-output-row: W' = q*s + L; s' = rowmax/127; W8 = round(W'/s').  K==4096.
// Register-resident w + wave shuffle reduction (1 barrier).
// ---------------------------------------------------------------------------
__global__ __launch_bounds__(256) void quant_w_kernel(
    const int* __restrict__ q, const float* __restrict__ scales,
    const __bf16* __restrict__ L, signed char* __restrict__ W8,
    float* __restrict__ sn, int K)
{
    const int o = blockIdx.x, t = threadIdx.x;
    const int lane = t & 63, wid = t >> 6;
    __shared__ float wm[4];

    const int4*   qr = (const int4*)(q + (long)o * K);
    const bf16x4* Lr = (const bf16x4*)(L + (long)o * K);
    const float   s  = scales[o];

    float w[16];
    float mx = 0.f;
    #pragma unroll
    for (int j = 0; j < 4; ++j) {
        int c = t + j * 256;
        int4   qv = qr[c];
        bf16x4 lv = Lr[c];
        w[4 * j + 0] = (float)qv.x * s + (float)lv[0];
        w[4 * j + 1] = (float)qv.y * s + (float)lv[1];
        w[4 * j + 2] = (float)qv.z * s + (float)lv[2];
        w[4 * j + 3] = (float)qv.w * s + (float)lv[3];
        mx = fmaxf(mx, fmaxf(fmaxf(fabsf(w[4 * j]), fabsf(w[4 * j + 1])),
                             fmaxf(fabsf(w[4 * j + 2]), fabsf(w[4 * j + 3]))));
    }
    #pragma unroll
    for (int off = 32; off; off >>= 1) mx = fmaxf(mx, __shfl_xor(mx, off));
    if (lane == 0) wm[wid] = mx;
    __syncthreads();
    const float gmax = fmaxf(fmaxf(fmaxf(wm[0], wm[1]), fmaxf(wm[2], wm[3])), 1e-30f);
    const float winv = 127.0f / gmax;

    int* wrow = (int*)(W8 + (long)o * K);
    #pragma unroll
    for (int j = 0; j < 4; ++j) {
        int c0 = (int)rintf(fminf(fmaxf(w[4 * j + 0] * winv, -127.f), 127.f));
        int c1 = (int)rintf(fminf(fmaxf(w[4 * j + 1] * winv, -127.f), 127.f));
        int c2 = (int)rintf(fminf(fmaxf(w[4 * j + 2] * winv, -127.f), 127.f));
        int c3 = (int)rintf(fminf(fmaxf(w[4 * j + 3] * winv, -127.f), 127.f));
        wrow[t + j * 256] = (c0 & 255) | ((c1 & 255) << 8) | ((c2 & 255) << 16) | (c3 << 24);
    }
    if (t == 0) sn[o] = gmax / 127.0f;
}

// ---------------------------------------------------------------------------
// Per-X-row: sx = rowmax|x|/127; X8 = round(x/sx).  K==4096.
// ---------------------------------------------------------------------------
__global__ __launch_bounds__(256) void quant_x_kernel(
    const float* __restrict__ X, signed char* __restrict__ X8,
    float* __restrict__ sxm, int K)
{
    const int m = blockIdx.x, t = threadIdx.x;
    const int lane = t & 63, wid = t >> 6;
    __shared__ float wm[4];

    const f32x4* xr = (const f32x4*)(X + (long)m * K);
    f32x4 v[4];
    float mx = 0.f;
    #pragma unroll
    for (int j = 0; j < 4; ++j) {
        v[j] = xr[t + j * 256];
        mx = fmaxf(mx, fmaxf(fmaxf(fabsf(v[j][0]), fabsf(v[j][1])),
                             fmaxf(fabsf(v[j][2]), fabsf(v[j][3]))));
    }
    #pragma unroll
    for (int off = 32; off; off >>= 1) mx = fmaxf(mx, __shfl_xor(mx, off));
    if (lane == 0) wm[wid] = mx;
    __syncthreads();
    const float gmax = fmaxf(fmaxf(fmaxf(wm[0], wm[1]), fmaxf(wm[2], wm[3])), 1e-30f);
    const float xinv = 127.0f / gmax;

    int* xrow = (int*)(X8 + (long)m * K);
    #pragma unroll
    for (int j = 0; j < 4; ++j) {
        int c0 = (int)rintf(fminf(fmaxf(v[j][0] * xinv, -127.f), 127.f));
        int c1 = (int)rintf(fminf(fmaxf(v[j][1] * xinv, -127.f), 127.f));
        int c2 = (int)rintf(fminf(fmaxf(v[j][2] * xinv, -127.f), 127.f));
        int c3 = (int)rintf(fminf(fmaxf(v[j][3] * xinv, -127.f), 127.f));
        xrow[t + j * 256] = (c0 & 255) | ((c1 & 255) << 8) | ((c2 & 255) << 16) | (c3 << 24);
    }
    if (t == 0) sxm[m] = gmax / 127.0f;
}

// ---------------------------------------------------------------------------
// INT8 GEMM (champion, 134 us): 256x256 tile, BK=128, 128B rows + 8-chunk
// XOR swizzle (verified conflict-free), flat tile body with SGB interleave
// hint, 1 barrier + 1 vmcnt per K-tile, dbuf 128KB.
// out = acc_i32 * sx[row]*s'[col] + bias[col].
// ---------------------------------------------------------------------------
#define VMW0  asm volatile("s_waitcnt vmcnt(0)" ::: "memory")
#define SB0   __builtin_amdgcn_sched_barrier(0)
#define SGB(mask, n) __builtin_amdgcn_sched_group_barrier((mask), (n), 0)

#define RD4(base, off) (*(const i32x4*)((base) + (off)))

#define MFI(mi, nj, A, B) \
    acc[mi][nj] = __builtin_amdgcn_mfma_i32_16x16x64_i8(A, B, acc[mi][nj], 0, 0, 0)

// stage one 256x128B operand (32KB) = 4 rounds of 8KB (512 thr x 16B)
#define STAGE_I8(dA, dB) do { \
    __builtin_amdgcn_global_load_lds(GLB(pB),          LDS((dB) + wb),         16, 0, 0); \
    __builtin_amdgcn_global_load_lds(GLB(pB + rk),     LDS((dB) + wb +  8192), 16, 0, 0); \
    __builtin_amdgcn_global_load_lds(GLB(pB + 2 * rk), LDS((dB) + wb + 16384), 16, 0, 0); \
    __builtin_amdgcn_global_load_lds(GLB(pB + 3 * rk), LDS((dB) + wb + 24576), 16, 0, 0); \
    __builtin_amdgcn_global_load_lds(GLB(pA),          LDS((dA) + wb),         16, 0, 0); \
    __builtin_amdgcn_global_load_lds(GLB(pA + rk),     LDS((dA) + wb +  8192), 16, 0, 0); \
    __builtin_amdgcn_global_load_lds(GLB(pA + 2 * rk), LDS((dA) + wb + 16384), 16, 0, 0); \
    __builtin_amdgcn_global_load_lds(GLB(pA + 3 * rk), LDS((dA) + wb + 24576), 16, 0, 0); } while (0)

#define ADVP8(a) do { pA += (a); pB += (a); } while (0)

// One K-tile (BK=128 = 2 k-slices of 64), no internal barriers.
#define TILE_I8(Ac, Bc, DOSTAGE) do { \
    const char* _ac = (Ac); const char* _bc = (Bc); \
    DOSTAGE; \
    __builtin_amdgcn_s_setprio(1); \
    { /* k-slice 0 */ \
      i32x4 b0 = RD4(_bc, bRow +    0 + kc0); \
      i32x4 b1 = RD4(_bc, bRow + 2048 + kc0); \
      i32x4 b2 = RD4(_bc, bRow + 4096 + kc0); \
      i32x4 b3 = RD4(_bc, bRow + 6144 + kc0); \
      i32x4 a0 = RD4(_ac, aRow +     0 + kc0); \
      i32x4 a1 = RD4(_ac, aRow +  2048 + kc0); \
      i32x4 a2 = RD4(_ac, aRow +  4096 + kc0); \
      i32x4 a3 = RD4(_ac, aRow +  6144 + kc0); \
      i32x4 a4 = RD4(_ac, aRow +  8192 + kc0); \
      i32x4 a5 = RD4(_ac, aRow + 10240 + kc0); \
      i32x4 a6 = RD4(_ac, aRow + 12288 + kc0); \
      i32x4 a7 = RD4(_ac, aRow + 14336 + kc0); \
      MFI(0,0,a0,b0); MFI(1,0,a1,b0); MFI(2,0,a2,b0); MFI(3,0,a3,b0); \
      MFI(4,0,a4,b0); MFI(5,0,a5,b0); MFI(6,0,a6,b0); MFI(7,0,a7,b0); \
      MFI(0,1,a0,b1); MFI(1,1,a1,b1); MFI(2,1,a2,b1); MFI(3,1,a3,b1); \
      MFI(4,1,a4,b1); MFI(5,1,a5,b1); MFI(6,1,a6,b1); MFI(7,1,a7,b1); \
      MFI(0,2,a0,b2); MFI(1,2,a1,b2); MFI(2,2,a2,b2); MFI(3,2,a3,b2); \
      MFI(4,2,a4,b2); MFI(5,2,a5,b2); MFI(6,2,a6,b2); MFI(7,2,a7,b2); \
      MFI(0,3,a0,b3); MFI(1,3,a1,b3); MFI(2,3,a2,b3); MFI(3,3,a3,b3); \
      MFI(4,3,a4,b3); MFI(5,3,a5,b3); MFI(6,3,a6,b3); MFI(7,3,a7,b3); \
    } \
    { /* k-slice 1 */ \
      i32x4 b0 = RD4(_bc, bRow +    0 + kc1); \
      i32x4 b1 = RD4(_bc, bRow + 2048 + kc1); \
      i32x4 b2 = RD4(_bc, bRow + 4096 + kc1); \
      i32x4 b3 = RD4(_bc, bRow + 6144 + kc1); \
      i32x4 a0 = RD4(_ac, aRow +     0 + kc1); \
      i32x4 a1 = RD4(_ac, aRow +  2048 + kc1); \
      i32x4 a2 = RD4(_ac, aRow +  4096 + kc1); \
      i32x4 a3 = RD4(_ac, aRow +  6144 + kc1); \
      i32x4 a4 = RD4(_ac, aRow +  8192 + kc1); \
      i32x4 a5 = RD4(_ac, aRow + 10240 + kc1); \
      i32x4 a6 = RD4(_ac, aRow + 12288 + kc1); \
      i32x4 a7 = RD4(_ac, aRow + 14336 + kc1); \
      MFI(0,0,a0,b0); MFI(1,0,a1,b0); MFI(2,0,a2,b0); MFI(3,0,a3,b0); \
      MFI(4,0,a4,b0); MFI(5,0,a5,b0); MFI(6,0,a6,b0); MFI(7,0,a7,b0); \
      MFI(0,1,a0,b1); MFI(1,1,a1,b1); MFI(2,1,a2,b1); MFI(3,1,a3,b1); \
      MFI(4,1,a4,b1); MFI(5,1,a5,b1); MFI(6,1,a6,b1); MFI(7,1,a7,b1); \
      MFI(0,2,a0,b2); MFI(1,2,a1,b2); MFI(2,2,a2,b2); MFI(3,2,a3,b2); \
      MFI(4,2,a4,b2); MFI(5,2,a5,b2); MFI(6,2,a6,b2); MFI(7,2,a7,b2); \
      MFI(0,3,a0,b3); MFI(1,3,a1,b3); MFI(2,3,a2,b3); MFI(3,3,a3,b3); \
      MFI(4,3,a4,b3); MFI(5,3,a5,b3); MFI(6,3,a6,b3); MFI(7,3,a7,b3); \
    } \
    SGB(0x30, 8); \
    SGB(0x100, 12); \
    SGB(0x8, 8); SGB(0x100, 3); \
    SGB(0x8, 8); SGB(0x100, 3); \
    SGB(0x8, 8); SGB(0x100, 3); \
    SGB(0x8, 8); SGB(0x100, 3); \
    SGB(0x8, 32); \
    __builtin_amdgcn_s_setprio(0); \
    VMW0; \
    __builtin_amdgcn_s_barrier(); \
    SB0; \
  } while (0)

__global__ __launch_bounds__(512, 2) void gemm_i8_kernel(
    const signed char* __restrict__ X8, const signed char* __restrict__ W8,
    const float* __restrict__ sxm, const float* __restrict__ sn,
    const float* __restrict__ bias, float* __restrict__ C,
    int M, int N, int K)
{
    // buf0 A [0,32K) B [32K,64K) | buf1 A [64K,96K) B [96K,128K)
    __shared__ __align__(16) char smem[131072];

    const int t = threadIdx.x, wid = t >> 6, lane = t & 63;
    const int wr = wid >> 2, wc = wid & 3;
    const int l15 = lane & 15, l7 = lane & 7, lk = lane >> 4;

    const int nwg = gridDim.x;
    int bid = blockIdx.x;
    if ((nwg & 7) == 0) bid = (bid & 7) * (nwg >> 3) + (bid >> 3);
    const int ntn = N >> 8;
    const int m0 = (bid / ntn) << 8, n0 = (bid % ntn) << 8;

    // staging: thread t sources row (t>>3)+64k, chunk (t&7)^((t>>3)&7)
    const int sr = t >> 3;
    const int ch = (t & 7) ^ (sr & 7);
    const long rk = 64L * K;                       // 64-row stride in bytes
    const signed char* pA = X8 + (long)(m0 + sr) * K + ch * 16;
    const signed char* pB = W8 + (long)(n0 + sr) * K + ch * 16;

    const int wb = wid * 1024;                     // wave-uniform stage base

    // fragment reads: row base+l15 (+16*mi), k-chunk (lk + 4*ks) ^ (row&7)
    const int aRow = (wr * 128 + l15) * 128;
    const int bRow = (wc * 64  + l15) * 128;
    const int kc0  = ((lk    ) ^ l7) << 4;
    const int kc1  = ((lk + 4) ^ l7) << 4;

    char* const bA0 = smem;
    char* const bB0 = smem + 32768;
    char* const bA1 = smem + 65536;
    char* const bB1 = smem + 98304;

    i32x4 acc[8][4] = {};

    const int nkt = K >> 7;                        // BK = 128

    STAGE_I8(bA0, bB0);
    ADVP8(nkt > 1 ? 128 : 0);
    VMW0;
    __builtin_amdgcn_s_barrier();
    SB0;

    for (int kt = 0; kt < nkt; kt += 2) {
        const long adv1 = (kt + 2 < nkt) ? 128 : 0;
        const long adv2 = (kt + 3 < nkt) ? 128 : 0;
        TILE_I8(bA0, bB0, { STAGE_I8(bA1, bB1); ADVP8(adv1); });
        TILE_I8(bA1, bB1, { STAGE_I8(bA0, bB0); ADVP8(adv2); });
    }

    // epilogue: col = lane&15 (+nj*16), row = (lane>>4)*4 + e (+mi*16)
    #pragma unroll
    for (int nj = 0; nj < 4; ++nj) {
        const int col = n0 + wc * 64 + nj * 16 + l15;
        const float scol = sn[col];
        const float bv   = bias[col];
        #pragma unroll
        for (int mi = 0; mi < 8; ++mi) {
            const long rowb = (long)m0 + wr * 128 + mi * 16 + (lane >> 4) * 4;
            const f32x4 sx4 = *(const f32x4*)(sxm + rowb);
            float* Cp = C + rowb * N + col;
            Cp[0]       = (float)acc[mi][nj][0] * (sx4[0] * scol) + bv;
            Cp[(long)N] = (float)acc[mi][nj][1] * (sx4[1] * scol) + bv;
            Cp[2L * N]  = (float)acc[mi][nj][2] * (sx4[2] * scol) + bv;
            Cp[3L * N]  = (float)acc[mi][nj][3] * (sx4[3] * scol) + bv;
        }
    }
}

// ---------------------------------------------------------------------------
// Last-resort fallback: on-the-fly dequant+LoRA fp32 GEMM (odd shapes / no ws).
// ---------------------------------------------------------------------------
__global__ __launch_bounds__(256) void fallback_gemm(
    const float* __restrict__ X, const int* __restrict__ q,
    const float* __restrict__ scales, const float* __restrict__ bias,
    const float* __restrict__ lA, const float* __restrict__ lB,
    float* __restrict__ C, int M, int N, int K)
{
    __shared__ float Xs[64][17];
    __shared__ float Ws[64][17];
    __shared__ float At[LORA_RANK][16];
    __shared__ float Bt[64][LORA_RANK];

    const int ntn = N >> 6;
    const int m0 = (blockIdx.x / ntn) << 6, n0 = (blockIdx.x % ntn) << 6;
    const int t = threadIdx.x;

    for (int j = t; j < 64 * LORA_RANK; j += 256)
        Bt[j >> 4][j & 15] = lB[(long)(n0 + (j >> 4)) * LORA_RANK + (j & 15)] * SCALING;

    const int tr = (t & 15) * 4, tc = (t >> 4) * 4;
    float acc[4][4] = {};

    for (int k0 = 0; k0 < K; k0 += 16) {
        __syncthreads();
        for (int j = t; j < 1024; j += 256)
            Xs[j >> 4][j & 15] = X[(long)(m0 + (j >> 4)) * K + k0 + (j & 15)];
        At[t >> 4][t & 15] = lA[(long)(t >> 4) * K + k0 + (t & 15)];
        __syncthreads();
        for (int j = t; j < 1024; j += 256) {
            int o = j >> 4, kk = j & 15;
            float v = (float)q[(long)(n0 + o) * K + k0 + kk] * scales[n0 + o];
            #pragma unroll
            for (int r = 0; r < LORA_RANK; ++r) v += Bt[o][r] * At[r][kk];
            Ws[o][kk] = v;
        }
        __syncthreads();
        #pragma unroll 4
        for (int kk = 0; kk < 16; ++kk)
            #pragma unroll
            for (int i = 0; i < 4; ++i)
                #pragma unroll
                for (int j = 0; j < 4; ++j)
                    acc[i][j] += Xs[tr + i][kk] * Ws[tc + j][kk];
    }
    __syncthreads();
    #pragma unroll
    for (int i = 0; i < 4; ++i)
        #pragma unroll
        for (int j = 0; j < 4; ++j)
            C[(long)(m0 + tr + i) * N + n0 + tc + j] = acc[i][j] + bias[n0 + tc + j];
}

// ---------------------------------------------------------------------------
extern "C" void kernel_launch(void* const* d_in, const int* in_sizes, int n_in,
                              void* d_out, int out_size, void* d_ws, size_t ws_size,
                              hipStream_t stream)
{
    const float* x      = (const float*)d_in[0];
    const int*   qw     = (const int*)d_in[1];
    const float* scales = (const float*)d_in[2];
    const float* bias   = (const float*)d_in[3];
    const float* lA     = (const float*)d_in[4];
    const float* lB     = (const float*)d_in[5];
    float*       out    = (float*)d_out;

    const int K = in_sizes[4] / LORA_RANK;   // 4096
    const int N = in_sizes[2];               // 4096
    const int M = in_sizes[0] / K;           // 8192

    const size_t i8need = (size_t)N * K + (size_t)M * K + (size_t)(M + N) * 4
                        + (size_t)N * K * 2 + 256;
    const bool i8_ok = (K == 4096) && (M % 256) == 0 && (N % 256) == 0 &&
                       ws_size >= i8need;

    if (i8_ok) {
        signed char* W8  = (signed char*)d_ws;
        signed char* X8  = W8 + (size_t)N * K;
        float*       sxm = (float*)(X8 + (size_t)M * K);
        float*       sn  = sxm + M;
        __bf16*      L   = (__bf16*)(sn + N);

        dim3 g1(K / 256, N / 64);
        lora_mat_kernel<<<g1, 256, 0, stream>>>(lA, lB, L, N, K);
        quant_w_kernel<<<N, 256, 0, stream>>>(qw, scales, L, W8, sn, K);
        quant_x_kernel<<<M, 256, 0, stream>>>(x, X8, sxm, K);
        const int nwg = (M / 256) * (N / 256);
        gemm_i8_kernel<<<nwg, 512, 0, stream>>>(X8, W8, sxm, sn, bias, out, M, N, K);
    } else {
        fallback_gemm<<<(M / 64) * (N / 64), 256, 0, stream>>>(
            x, qw, scales, bias, lA, lB, out, M, N, K);
    }
}